// Round 7
// baseline (1907.002 us; speedup 1.0000x reference)
//
#include <hip/hip_runtime.h>
#include <math.h>

#define BD 8
#define ND 1024
#define KNN 20
#define NEGS 0.2f
#define BNSC 0.99999500003749969482f
#define KSL 8      // key slices for flash-decode attention
#define KPS 128    // keys per slice

__device__ __forceinline__ float leakyf(float y){ return y >= 0.f ? y : NEGS*y; }

// -------- fused input slice + transpose + xx: x[b,n,c]=feat[b,c0+c,n] (padded CS) ----
template<int C, int CS>
__global__ __launch_bounds__(256) void k_prep(const float* __restrict__ feat,
                                              float* __restrict__ x,
                                              float* __restrict__ xx, int c0){
  int i = blockIdx.x*256 + threadIdx.x;
  if (i >= BD*ND) return;
  int b = i >> 10, n = i & 1023;
  float v[CS];
  float s = 0.f;
  #pragma unroll
  for (int c = 0; c < C; ++c){
    v[c] = feat[((size_t)(b*15) + c0 + c)*ND + n];
    s = fmaf(v[c], v[c], s);
  }
  #pragma unroll
  for (int c = C; c < CS; ++c) v[c] = 0.f;
  #pragma unroll
  for (int c = 0; c < CS; c += 4)
    *(float4*)&x[(size_t)i*CS + c] = make_float4(v[c], v[c+1], v[c+2], v[c+3]);
  xx[i] = s;
}

// -------- fused gram + exact top-20: double-buffered LDS + pipelined reads -----------
// block = 16 rows (4 waves x 4 rows); columns staged in 2x(16KB+16KB) ping-pong.
__global__ __launch_bounds__(256, 2) void k_knn(const float* __restrict__ x,
    const float* __restrict__ xx, int* __restrict__ idxp, int CS, int nchunk){
  __shared__ __align__(16) float Xc0[2][1024*4];   // 32 KB
  __shared__ __align__(16) float Xc1[2][1024*4];   // 32 KB
  int b = blockIdx.y;
  int r0 = blockIdx.x*16;
  int t = threadIdx.x;
  int lane = t & 63, w = t >> 6;
  float acc[4][16];
  #pragma unroll
  for (int j = 0; j < 4; ++j)
    #pragma unroll
    for (int q = 0; q < 16; ++q) acc[j][q] = 0.f;
  const float* xb = x + (size_t)b*ND*CS;
  // stage chunk 0 into buffer 0
  {
    bool h1 = (4 < CS);
    #pragma unroll
    for (int i = 0; i < 4; ++i){
      int m = t + i*256;
      const float* xp = &xb[(size_t)m*CS];
      float4 v0 = *(const float4*)xp;
      float4 v1 = h1 ? *(const float4*)(xp + 4) : make_float4(0.f,0.f,0.f,0.f);
      *(float4*)&Xc0[0][m*4] = v0;
      *(float4*)&Xc1[0][m*4] = v1;
    }
  }
  __syncthreads();
  for (int ch = 0; ch < nchunk; ++ch){
    int cur = ch & 1;
    // issue next chunk's staging loads NOW (latency overlaps this chunk's compute)
    float4 s0[4], s1[4];
    bool more = (ch + 1 < nchunk);
    if (more){
      int c0n = (ch+1)*8;
      bool h1n = (c0n + 4 < CS);
      #pragma unroll
      for (int i = 0; i < 4; ++i){
        int m = t + i*256;
        const float* xp = &xb[(size_t)m*CS + c0n];
        s0[i] = *(const float4*)xp;
        s1[i] = h1n ? *(const float4*)(xp + 4) : make_float4(0.f,0.f,0.f,0.f);
      }
    }
    // row fragments (broadcast reads, cheap)
    float4 rv0[4], rv1[4];
    #pragma unroll
    for (int j = 0; j < 4; ++j){
      int r = (r0 + w*4 + j)*4;
      rv0[j] = *(const float4*)&Xc0[cur][r];
      rv1[j] = *(const float4*)&Xc1[cur][r];
    }
    // pipelined col loop: prefetch q+1 while fma-ing q
    float4 nb0 = *(const float4*)&Xc0[cur][lane*4];
    float4 nb1 = *(const float4*)&Xc1[cur][lane*4];
    #pragma unroll
    for (int q = 0; q < 16; ++q){
      float4 cv0 = nb0, cv1 = nb1;
      if (q < 15){
        nb0 = *(const float4*)&Xc0[cur][((q+1)*64 + lane)*4];
        nb1 = *(const float4*)&Xc1[cur][((q+1)*64 + lane)*4];
      }
      #pragma unroll
      for (int j = 0; j < 4; ++j){
        float s = acc[j][q];
        s = fmaf(rv0[j].x, cv0.x, s); s = fmaf(rv0[j].y, cv0.y, s);
        s = fmaf(rv0[j].z, cv0.z, s); s = fmaf(rv0[j].w, cv0.w, s);
        s = fmaf(rv1[j].x, cv1.x, s); s = fmaf(rv1[j].y, cv1.y, s);
        s = fmaf(rv1[j].z, cv1.z, s); s = fmaf(rv1[j].w, cv1.w, s);
        acc[j][q] = s;
      }
    }
    // commit staged regs to the other buffer (safe: it was last read in ch-1,
    // and the barrier at the end of ch-1 proved everyone finished with it)
    if (more){
      int nxt = cur ^ 1;
      #pragma unroll
      for (int i = 0; i < 4; ++i){
        int m = t + i*256;
        *(float4*)&Xc0[nxt][m*4] = s0[i];
        *(float4*)&Xc1[nxt][m*4] = s1[i];
      }
    }
    __syncthreads();
  }
  // transform to negdist = 2*dot - xx_r - xx_m, then to sortable uints
  float xxm[16];
  #pragma unroll
  for (int q = 0; q < 16; ++q) xxm[q] = xx[b*ND + q*64 + lane];
  unsigned uk[4][16];
  #pragma unroll
  for (int j = 0; j < 4; ++j){
    float xr = xx[b*ND + r0 + w*4 + j];
    #pragma unroll
    for (int q = 0; q < 16; ++q){
      float f = 2.f*acc[j][q] - xr - xxm[q];
      unsigned bv = __float_as_uint(f);
      uk[j][q] = (bv & 0x80000000u) ? ~bv : (bv | 0x80000000u);  // order-preserving
    }
  }
  // radix binary search for T = 20th-largest key per row; counts via ballot+scalar
  unsigned pref[4] = {0u, 0u, 0u, 0u};
  #pragma unroll 1
  for (int bit = 31; bit >= 0; --bit){
    #pragma unroll
    for (int u = 0; u < 4; ++u){
      unsigned cand = pref[u] | (1u << bit);
      int c = 0;
      #pragma unroll
      for (int q = 0; q < 16; ++q)
        c += (int)__popcll(__ballot(uk[u][q] >= cand));
      if (c >= KNN) pref[u] = cand;
    }
  }
  // emit: all keys > T, plus lowest-global-index keys == T to fill to 20
  unsigned long long mlt = (1ull << lane) - 1ull;   // lanes below me
  #pragma unroll
  for (int u = 0; u < 4; ++u){
    unsigned T = pref[u];
    int cg = 0;
    #pragma unroll
    for (int q = 0; q < 16; ++q) cg += (int)__popcll(__ballot(uk[u][q] > T));
    int need_eq = KNN - cg;                          // >= 1 by construction
    int* op = &idxp[((size_t)(b*ND + r0 + w*4 + u))*KNN];
    int run_gt = 0, run_eq = 0;
    #pragma unroll
    for (int q = 0; q < 16; ++q){
      unsigned k = uk[u][q];
      unsigned long long bg = __ballot(k > T);
      unsigned long long be = __ballot(k == T);
      if (k > T) op[run_gt + (int)__popcll(bg & mlt)] = q*64 + lane;
      if (k == T){
        int r = run_eq + (int)__popcll(be & mlt);
        if (r < need_eq) op[cg + r] = q*64 + lane;
      }
      run_gt += (int)__popcll(bg);
      run_eq += (int)__popcll(be);
    }
  }
}

// ------ phase A (register-blocked): zs=alpha*W1.x ; cc=(dW.x+bias)*alpha+beta --------
template<int O>
__global__ __launch_bounds__(256) void k_phaseA(const float* __restrict__ x,
    const float* __restrict__ W, const float* __restrict__ bias,
    const float* __restrict__ gamma, const float* __restrict__ beta,
    float* __restrict__ zs, float* __restrict__ ccv, int C, int XS){
  constexpr int TO = O/16;
  constexpr int WP = O + 4;
  __shared__ float W1s[32*WP];
  __shared__ float dWs[32*WP];
  __shared__ float Xs[32*33];
  int blk = blockIdx.x;
  int b = blk >> 5, n0 = (blk & 31)*32;
  int t = threadIdx.x;
  int ot = t & 15, nt = t >> 4;
  int obase = ot*TO;
  int nl = nt*2;
  float az[TO][2] = {}, ac[TO][2] = {};
  for (int cc = 0; cc < C; cc += 32){
    int KC = (C - cc < 32) ? (C - cc) : 32;
    for (int i = t; i < O*KC; i += 256){
      int o = i % O, c = i / O;
      float w1 = W[(size_t)o*2*C + cc + c];
      float w2 = W[(size_t)o*2*C + C + cc + c];
      W1s[c*WP + o] = w1;
      dWs[c*WP + o] = w2 - w1;
    }
    for (int i = t; i < 32*KC; i += 256){
      int c = i % KC, row = i / KC;
      Xs[c*33 + row] = x[((size_t)b*ND + n0 + row)*XS + cc + c];
    }
    __syncthreads();
    for (int c = 0; c < KC; ++c){
      float xv0 = Xs[c*33 + nl];
      float xv1 = Xs[c*33 + nl + 1];
      #pragma unroll
      for (int i = 0; i < TO; ++i){
        float w1 = W1s[c*WP + obase + i];
        float dw = dWs[c*WP + obase + i];
        az[i][0] = fmaf(w1, xv0, az[i][0]);
        az[i][1] = fmaf(w1, xv1, az[i][1]);
        ac[i][0] = fmaf(dw, xv0, ac[i][0]);
        ac[i][1] = fmaf(dw, xv1, ac[i][1]);
      }
    }
    __syncthreads();
  }
  #pragma unroll
  for (int i = 0; i < TO; ++i){
    int o = obase + i;
    float alpha = gamma[o]*BNSC;
    float bb = bias[o], be = beta[o];
    #pragma unroll
    for (int q = 0; q < 2; ++q){
      int n = n0 + nl + q;
      size_t off = ((size_t)b*ND + n)*O + o;
      zs[off]  = az[i][q]*alpha;
      ccv[off] = fmaf(ac[i][q] + bb, alpha, be);
    }
  }
}

// ------ phase B: out[b,n,o] = max_k leaky(zs[b,idx_k,o]+cc[b,n,o]); optional xx ------
template<bool DOXX>
__global__ __launch_bounds__(256) void k_phaseB(const float* __restrict__ zs,
    const float* __restrict__ ccv, const int* __restrict__ idxp,
    float* __restrict__ outp, float* __restrict__ xxout,
    int O, int ostride, int ooff){
  int t = threadIdx.x;
  int lane = t & 63, w = t >> 6;
  int gn = blockIdx.x*4 + w;
  int b = gn >> 10;
  int mm[KNN];
  const int* ip = idxp + (size_t)gn*KNN;
  #pragma unroll
  for (int k = 0; k < KNN; ++k) mm[k] = ip[k];
  float sq = 0.f;
  for (int o = lane; o < O; o += 64){
    float cvv = ccv[(size_t)gn*O + o];
    float mx = -INFINITY;
    #pragma unroll 4
    for (int k = 0; k < KNN; ++k){
      float v = leakyf(zs[((size_t)(b*ND) + mm[k])*O + o] + cvv);
      mx = fmaxf(mx, v);
    }
    outp[(size_t)gn*ostride + ooff + o] = mx;
    if (DOXX) sq = fmaf(mx, mx, sq);
  }
  if (DOXX){
    #pragma unroll
    for (int off = 32; off; off >>= 1) sq += __shfl_down(sq, off);
    if (lane == 0) xxout[gn] = sq;
  }
}

// ---------------- qkv[bn,o] = fuse[bn,:].Wi[o,:] + bi[o]  (raw Wi, float4) -----------
__global__ __launch_bounds__(256) void k_lin(const float* __restrict__ in,
    const float* __restrict__ Wm, const float* __restrict__ bias,
    float* __restrict__ outp){
  int gid = blockIdx.x*256 + threadIdx.x;
  if (gid >= BD*ND*192) return;
  int o = gid % 192; int bn = gid / 192;
  const float4* ip = (const float4*)(in + (size_t)bn*64);
  const float4* wp = (const float4*)(Wm + (size_t)o*64);
  float s = bias[o];
  #pragma unroll
  for (int c = 0; c < 16; ++c){
    float4 a = ip[c], wv = wp[c];
    s = fmaf(a.x, wv.x, s); s = fmaf(a.y, wv.y, s);
    s = fmaf(a.z, wv.z, s); s = fmaf(a.w, wv.w, s);
  }
  outp[gid] = s;
}

// ------- flash-decode attention (no-max exp): 2 heads/block, 8 queries/thread --------
__global__ __launch_bounds__(256, 1) void k_attn_part(const float* __restrict__ qkv,
    float* __restrict__ pl, float* __restrict__ pacc){
  __shared__ __align__(16) float Ks[2][KPS*8];
  __shared__ __align__(16) float Vs[2][KPS*8];
  int blk = blockIdx.x;                // b(8) x hp(4) x ksl(8) = 256 blocks
  int ksl = blk & 7; int hp = (blk >> 3) & 3; int b = blk >> 5;
  int t = threadIdx.x;
  int hh = t >> 7;                     // wave-uniform head select within pair
  int h = hp*2 + hh;
  int lq = t & 127;
  for (int i = t; i < 2*KPS*8; i += 256){
    int hi = (i >= KPS*8) ? 1 : 0;
    int r = i - hi*KPS*8;
    int m = r >> 3, dd = r & 7;
    size_t base = ((size_t)b*ND + ksl*KPS + m)*192 + (hp*2 + hi)*8 + dd;
    Ks[hi][r] = qkv[base + 64];
    Vs[hi][r] = qkv[base + 128];
  }
  __syncthreads();
  const float scale = 0.35355339059327373f;
  float q[8][8];
  #pragma unroll
  for (int u = 0; u < 8; ++u){
    int n = u*128 + lq;
    const float4* qp = (const float4*)(qkv + ((size_t)b*ND + n)*192 + h*8);
    float4 q0 = qp[0], q1 = qp[1];
    q[u][0]=q0.x*scale; q[u][1]=q0.y*scale; q[u][2]=q0.z*scale; q[u][3]=q0.w*scale;
    q[u][4]=q1.x*scale; q[u][5]=q1.y*scale; q[u][6]=q1.z*scale; q[u][7]=q1.w*scale;
  }
  float l[8] = {};
  float acc[8][8] = {};
  for (int m = 0; m < KPS; ++m){
    float4 k0 = *(const float4*)&Ks[hh][m*8];
    float4 k1 = *(const float4*)&Ks[hh][m*8+4];
    float4 v0 = *(const float4*)&Vs[hh][m*8];
    float4 v1 = *(const float4*)&Vs[hh][m*8+4];
    #pragma unroll
    for (int u = 0; u < 8; ++u){
      float s;
      s = q[u][0]*k0.x;           s = fmaf(q[u][1], k0.y, s);
      s = fmaf(q[u][2], k0.z, s); s = fmaf(q[u][3], k0.w, s);
      s = fmaf(q[u][4], k1.x, s); s = fmaf(q[u][5], k1.y, s);
      s = fmaf(q[u][6], k1.z, s); s = fmaf(q[u][7], k1.w, s);
      float p = __expf(s);        // scores tiny: exp-without-max is safe; merge = sum
      l[u] += p;
      acc[u][0] = fmaf(p, v0.x, acc[u][0]);
      acc[u][1] = fmaf(p, v0.y, acc[u][1]);
      acc[u][2] = fmaf(p, v0.z, acc[u][2]);
      acc[u][3] = fmaf(p, v0.w, acc[u][3]);
      acc[u][4] = fmaf(p, v1.x, acc[u][4]);
      acc[u][5] = fmaf(p, v1.y, acc[u][5]);
      acc[u][6] = fmaf(p, v1.z, acc[u][6]);
      acc[u][7] = fmaf(p, v1.w, acc[u][7]);
    }
  }
  #pragma unroll
  for (int u = 0; u < 8; ++u){
    int n = u*128 + lq;
    size_t pidx = (((size_t)(b*8 + h))*8 + ksl)*ND + n;
    pl[pidx] = l[u];
    float4* ap = (float4*)&pacc[pidx*8];
    ap[0] = make_float4(acc[u][0], acc[u][1], acc[u][2], acc[u][3]);
    ap[1] = make_float4(acc[u][4], acc[u][5], acc[u][6], acc[u][7]);
  }
}

// ------- flash-decode combine: plain sums (no max bookkeeping) -----------------------
__global__ __launch_bounds__(256) void k_attn_comb(const float* __restrict__ pl,
    const float* __restrict__ pacc, float* __restrict__ attno){
  int gid = blockIdx.x*256 + threadIdx.x;   // (b*8+h)*1024+n, total 65536
  if (gid >= BD*8*ND) return;
  int n = gid & 1023; int bh = gid >> 10;
  int h = bh & 7; int b = bh >> 3;
  float L = 0.f;
  float o[8] = {};
  #pragma unroll
  for (int s = 0; s < KSL; ++s){
    size_t pidx = ((size_t)bh*8 + s)*ND + n;
    L += pl[pidx];
    const float4* ap = (const float4*)&pacc[pidx*8];
    float4 a0 = ap[0], a1 = ap[1];
    o[0] += a0.x; o[1] += a0.y; o[2] += a0.z; o[3] += a0.w;
    o[4] += a1.x; o[5] += a1.y; o[6] += a1.z; o[7] += a1.w;
  }
  float inv = 1.f/L;
  float4* dst = (float4*)&attno[((size_t)b*ND + n)*64 + h*8];
  dst[0] = make_float4(o[0]*inv, o[1]*inv, o[2]*inv, o[3]*inv);
  dst[1] = make_float4(o[4]*inv, o[5]*inv, o[6]*inv, o[7]*inv);
}

// ------- out-proj + pair-mean: emb[bn,f] = 0.5*(proj[2f]+proj[2f+1]) (raw Wo) --------
__global__ __launch_bounds__(256) void k_projmean(const float* __restrict__ attno,
    const float* __restrict__ Wo, const float* __restrict__ bo,
    float* __restrict__ emb){
  int gid = blockIdx.x*256 + threadIdx.x;
  if (gid >= BD*ND*32) return;
  int f = gid % 32; int bn = gid / 32;
  const float4* ip = (const float4*)(attno + (size_t)bn*64);
  int o0 = 2*f, o1 = 2*f + 1;
  const float4* w0 = (const float4*)(Wo + (size_t)o0*64);
  const float4* w1 = (const float4*)(Wo + (size_t)o1*64);
  float s0 = bo[o0], s1 = bo[o1];
  #pragma unroll
  for (int c = 0; c < 16; ++c){
    float4 a = ip[c], u = w0[c], v = w1[c];
    s0 = fmaf(a.x,u.x,s0); s0 = fmaf(a.y,u.y,s0); s0 = fmaf(a.z,u.z,s0); s0 = fmaf(a.w,u.w,s0);
    s1 = fmaf(a.x,v.x,s1); s1 = fmaf(a.y,v.y,s1); s1 = fmaf(a.z,v.z,s1); s1 = fmaf(a.w,v.w,s1);
  }
  emb[gid] = 0.5f*(s0 + s1);
}

// ---------------- fused attention pool: g, scores, pooled (one block per b) ----------
__global__ __launch_bounds__(256) void k_poolfuse(const float* __restrict__ emb,
    const float* __restrict__ attw, float* __restrict__ sout,
    float* __restrict__ pooled){
  __shared__ float part[8][32];
  __shared__ float meanv[32];
  __shared__ float gv[32];
  __shared__ float sc[ND];
  int b = blockIdx.x, t = threadIdx.x;
  int f = t & 31, j = t >> 5;
  const float* eb = emb + (size_t)b*ND*32;
  float s = 0.f;
  for (int n = j; n < ND; n += 8) s += eb[n*32 + f];
  part[j][f] = s;
  __syncthreads();
  if (t < 32){
    float m = 0.f;
    for (int j2 = 0; j2 < 8; ++j2) m += part[j2][t];
    meanv[t] = m * (1.f/ND);
  }
  __syncthreads();
  if (t < 32){
    float acc = 0.f;
    for (int f2 = 0; f2 < 32; ++f2) acc = fmaf(meanv[f2], attw[f2*32 + t], acc);
    gv[t] = tanhf(acc);
  }
  __syncthreads();
  for (int n = t; n < ND; n += 256){
    const float4* ep = (const float4*)(eb + n*32);
    float acc = 0.f;
    #pragma unroll
    for (int f4 = 0; f4 < 8; ++f4){
      float4 e = ep[f4];
      acc = fmaf(e.x, gv[f4*4+0], acc);
      acc = fmaf(e.y, gv[f4*4+1], acc);
      acc = fmaf(e.z, gv[f4*4+2], acc);
      acc = fmaf(e.w, gv[f4*4+3], acc);
    }
    float sg = 1.f/(1.f + __expf(-acc));
    sout[b*ND + n] = sg;
    sc[n] = sg;
  }
  __syncthreads();
  float pacc = 0.f;
  for (int n = j; n < ND; n += 8) pacc = fmaf(eb[n*32 + f], sc[n], pacc);
  part[j][f] = pacc;
  __syncthreads();
  if (t < 32){
    float m = 0.f;
    for (int j2 = 0; j2 < 8; ++j2) m += part[j2][t];
    pooled[b*32 + t] = m;
  }
}

// ---------------- NTN head: LDS-staged weights (2-phase, 32KB each) ----------------
__global__ __launch_bounds__(256) void k_head(const float* __restrict__ p1,
    const float* __restrict__ p2, const float* __restrict__ ntnw,
    const float* __restrict__ ntnv, const float* __restrict__ ntnb,
    const float* __restrict__ fc1w, const float* __restrict__ fc1b,
    const float* __restrict__ scw, const float* __restrict__ scb,
    float* __restrict__ outscore){
  __shared__ __align__(16) float Wl[8192];
  __shared__ float Vl[512];
  __shared__ float F1[256];
  __shared__ float ds[8][32];
  __shared__ float tv[8][16];
  __shared__ float hv[8][16];
  int t = threadIdx.x;
  {
    int b = t >> 5, f = t & 31;
    ds[b][f] = p1[b*32+f] - p2[b*32+f];
  }
  for (int i = t; i < 512; i += 256) Vl[i] = ntnv[i];
  if (t < 256) F1[t] = fc1w[t];
  float acc = 0.f;
  for (int ph = 0; ph < 2; ++ph){
    __syncthreads();
    {
      const float4* src = (const float4*)(ntnw + ph*8192);
      float4* dst = (float4*)Wl;
      for (int i = t; i < 2048; i += 256) dst[i] = src[i];
    }
    __syncthreads();
    if (t < 128){
      int b = t >> 4, tt = t & 15;
      for (int fi = 0; fi < 16; ++fi){
        float df = ds[b][ph*16 + fi];
        #pragma unroll 8
        for (int gg = 0; gg < 32; ++gg)
          acc = fmaf(df*ds[b][gg], Wl[(fi*32+gg)*16 + tt], acc);
      }
    }
  }
  if (t < 128){
    int b = t >> 4, tt = t & 15;
    acc += ntnb[tt];
    for (int gg = 0; gg < 32; ++gg) acc = fmaf(ds[b][gg], Vl[tt*32+gg], acc);
    tv[b][tt] = fmaxf(acc, 0.f);
  }
  __syncthreads();
  if (t < 128){
    int b = t >> 4, i = t & 15;
    float a2 = fc1b[i];
    for (int kk = 0; kk < 16; ++kk) a2 = fmaf(tv[b][kk], F1[i*16+kk], a2);
    hv[b][i] = fmaxf(a2, 0.f);
  }
  __syncthreads();
  if (t < 8){
    float a3 = scb[0];
    for (int i = 0; i < 16; ++i) a3 = fmaf(hv[t][i], scw[i], a3);
    outscore[t] = 1.f/(1.f + __expf(-a3));
  }
}

// =====================================================================================
extern "C" void kernel_launch(void* const* d_in, const int* in_sizes, int n_in,
                              void* d_out, int out_size, void* d_ws, size_t ws_size,
                              hipStream_t stream) {
  auto F = [&](int i){ return (const float*)d_in[i]; };
  const float* feats[2] = { F(0), F(1) };
  const float* cw[3] = { F(2), F(6), F(10) };
  const float* cb[3] = { F(3), F(7), F(11) };
  const float* cg[3] = { F(4), F(8), F(12) };
  const float* cB[3] = { F(5), F(9), F(13) };
  const float* sw[3] = { F(14), F(18), F(22) };
  const float* sb[3] = { F(15), F(19), F(23) };
  const float* sg[3] = { F(16), F(20), F(24) };
  const float* sB[3] = { F(17), F(21), F(25) };
  const float* mha_wi = F(26); const float* mha_bi = F(27);
  const float* mha_wo = F(28); const float* mha_bo = F(29);
  const float* att_w  = F(30);
  const float* ntn_w  = F(31); const float* ntn_v = F(32); const float* ntn_b = F(33);
  const float* fc1_w  = F(34); const float* fc1_b = F(35);
  const float* sc_w   = F(36); const float* sc_b  = F(37);
  float* out = (float*)d_out;

  char* ws = (char*)d_ws;
  // MHA scratch in the low region (formerly negdist; knn no longer writes it)
  float* qkv   = (float*)ws;                              // [0, 6 MiB)
  float* attno = (float*)(ws + ((size_t)8  << 20));       // [8, 10 MiB)
  float* plb   = (float*)(ws + ((size_t)10 << 20));       // [10, 12 MiB)
  float* paccb = (float*)(ws + ((size_t)14 << 20));       // [14, 30 MiB)
  size_t off = 33554432;
  float* xA   = (float*)(ws + off); off += 4194304;
  float* xB   = (float*)(ws + off); off += 4194304;
  float* zs   = (float*)(ws + off); off += 4194304;
  float* cvb  = (float*)(ws + off); off += 4194304;
  int*   idxb = (int*)  (ws + off); off += 655360;
  float* xxb  = (float*)(ws + off); off += 32768;
  float* fuse = (float*)(ws + off); off += 2097152;
  float* emb1 = (float*)(ws + off); off += 1048576;
  float* emb2 = (float*)(ws + off); off += 1048576;
  float* pool1= (float*)(ws + off); off += 4096;
  float* pool2= (float*)(ws + off); off += 4096;

  auto knn = [&](const float* xin, int CS, int nch){
    k_knn<<<dim3(64, 8), 256, 0, stream>>>(xin, xxb, idxb, CS, nch);
  };
  auto phA = [&](const float* xin, int C, int XS, int O, const float* W, const float* bb,
                 const float* gg, const float* be){
    if (O == 64)       k_phaseA<64> <<<BD*ND/32, 256, 0, stream>>>(xin, W, bb, gg, be, zs, cvb, C, XS);
    else if (O == 128) k_phaseA<128><<<BD*ND/32, 256, 0, stream>>>(xin, W, bb, gg, be, zs, cvb, C, XS);
    else               k_phaseA<32> <<<BD*ND/32, 256, 0, stream>>>(xin, W, bb, gg, be, zs, cvb, C, XS);
  };

  for (int br = 0; br < 2; ++br){
    const float* feat = feats[br];
    float* emb    = br ? emb2  : emb1;
    float* sout   = out + 8 + br*(BD*ND);
    float* pooled = br ? pool2 : pool1;
    for (int part = 0; part < 2; ++part){
      const float* const* Wl = part ? sw : cw;
      const float* const* bl = part ? sb : cb;
      const float* const* gl = part ? sg : cg;
      const float* const* Bl = part ? sB : cB;
      int C0 = part ? 12 : 3;
      int CS0 = part ? 12 : 4;
      // layer 0: C0 -> 64
      if (part) k_prep<12,12><<<BD*ND/256, 256, 0, stream>>>(feat, xA, xxb, 3);
      else      k_prep<3, 4> <<<BD*ND/256, 256, 0, stream>>>(feat, xA, xxb, 0);
      knn(xA, CS0, part ? 2 : 1);
      phA(xA, C0, CS0, 64, Wl[0], bl[0], gl[0], Bl[0]);
      k_phaseB<true><<<BD*ND/4, 256, 0, stream>>>(zs, cvb, idxb, xB, xxb, 64, 64, 0);
      // layer 1: 64 -> 128 (xx produced by phaseB)
      knn(xB, 64, 8);
      phA(xB, 64, 64, 128, Wl[1], bl[1], gl[1], Bl[1]);
      k_phaseB<true><<<BD*ND/4, 256, 0, stream>>>(zs, cvb, idxb, xA, xxb, 128, 128, 0);
      // layer 2: 128 -> 32, written into fuse at column offset
      knn(xA, 128, 16);
      phA(xA, 128, 128, 32, Wl[2], bl[2], gl[2], Bl[2]);
      k_phaseB<false><<<BD*ND/4, 256, 0, stream>>>(zs, cvb, idxb, fuse, nullptr, 32, 64, part*32);
    }
    // MHA (flash-decode, no-max exp)
    k_lin<<<(BD*ND*192)/256, 256, 0, stream>>>(fuse, mha_wi, mha_bi, qkv);
    k_attn_part<<<BD*4*KSL, 256, 0, stream>>>(qkv, plb, paccb);
    k_attn_comb<<<(BD*8*ND)/256, 256, 0, stream>>>(plb, paccb, attno);
    k_projmean<<<(BD*ND*32)/256, 256, 0, stream>>>(attno, mha_wo, mha_bo, emb);
    // fused attention pool
    k_poolfuse<<<BD, 256, 0, stream>>>(emb, att_w, sout, pooled);
  }
  k_head<<<1, 256, 0, stream>>>(pool1, pool2, ntn_w, ntn_v, ntn_b,
                                fc1_w, fc1_b, sc_w, sc_b, out);
}

// Round 8
// 1543.982 us; speedup vs baseline: 1.2351x; 1.2351x over previous
//
#include <hip/hip_runtime.h>
#include <math.h>

#define BD 8
#define ND 1024
#define KNN 20
#define NEGS 0.2f
#define BNSC 0.99999500003749969482f
#define KSL 8      // key slices for flash-decode attention
#define KPS 128    // keys per slice

__device__ __forceinline__ float leakyf(float y){ return y >= 0.f ? y : NEGS*y; }

// -------- fused input slice + transpose + xx: x[b,n,c]=feat[b,c0+c,n] (padded CS) ----
template<int C, int CS>
__global__ __launch_bounds__(256) void k_prep(const float* __restrict__ feat,
                                              float* __restrict__ x,
                                              float* __restrict__ xx, int c0){
  int i = blockIdx.x*256 + threadIdx.x;
  if (i >= BD*ND) return;
  int b = i >> 10, n = i & 1023;
  float v[CS];
  float s = 0.f;
  #pragma unroll
  for (int c = 0; c < C; ++c){
    v[c] = feat[((size_t)(b*15) + c0 + c)*ND + n];
    s = fmaf(v[c], v[c], s);
  }
  #pragma unroll
  for (int c = C; c < CS; ++c) v[c] = 0.f;
  #pragma unroll
  for (int c = 0; c < CS; c += 4)
    *(float4*)&x[(size_t)i*CS + c] = make_float4(v[c], v[c+1], v[c+2], v[c+3]);
  xx[i] = s;
}

// -------- fused gram + exact top-20: rows in SGPRs (wave-uniform), cols in LDS -------
// block = 16 rows (4 waves x 4 rows); cols staged as two 16B-stride LDS arrays.
__global__ __launch_bounds__(256) __attribute__((amdgpu_waves_per_eu(2, 2)))
void k_knn(const float* __restrict__ x,
    const float* __restrict__ xx, int* __restrict__ idxp, int CS, int nchunk){
  __shared__ __align__(16) float Xc0[1024*4];   // 16 KB: cols, floats c0..c0+3
  __shared__ __align__(16) float Xc1[1024*4];   // 16 KB: cols, floats c0+4..c0+7
  int b = blockIdx.y;
  int r0 = blockIdx.x*16;
  int t = threadIdx.x;
  int lane = t & 63;
  int w = __builtin_amdgcn_readfirstlane(t >> 6);   // wave-uniform wave id
  float acc[4][16];
  #pragma unroll
  for (int j = 0; j < 4; ++j)
    #pragma unroll
    for (int q = 0; q < 16; ++q) acc[j][q] = 0.f;
  const float* xb = x + (size_t)b*ND*CS;
  for (int ch = 0; ch < nchunk; ++ch){
    int c0 = ch*8;
    bool h1 = (c0 + 4 < CS);
    __syncthreads();
    for (int m = t; m < 1024; m += 256){
      const float* xp = &xb[(size_t)m*CS + c0];
      float4 v0 = *(const float4*)xp;
      float4 v1 = h1 ? *(const float4*)(xp + 4) : make_float4(0.f,0.f,0.f,0.f);
      *(float4*)&Xc0[m*4] = v0;   // lane stride 16B: conflict-free (verified r5/r6)
      *(float4*)&Xc1[m*4] = v1;
    }
    __syncthreads();
    // row fragments: wave-uniform GLOBAL loads -> scalar regs (no VGPR/LDS cost)
    float4 rv0[4], rv1[4];
    #pragma unroll
    for (int j = 0; j < 4; ++j){
      const float* rp = &xb[(size_t)(r0 + w*4 + j)*CS + c0];
      rv0[j] = *(const float4*)rp;
      rv1[j] = h1 ? *(const float4*)(rp + 4) : make_float4(0.f,0.f,0.f,0.f);
    }
    #pragma unroll
    for (int q = 0; q < 16; ++q){
      float4 cv0 = *(const float4*)&Xc0[(q*64 + lane)*4];
      float4 cv1 = *(const float4*)&Xc1[(q*64 + lane)*4];
      #pragma unroll
      for (int j = 0; j < 4; ++j){
        float s = acc[j][q];
        s = fmaf(rv0[j].x, cv0.x, s); s = fmaf(rv0[j].y, cv0.y, s);
        s = fmaf(rv0[j].z, cv0.z, s); s = fmaf(rv0[j].w, cv0.w, s);
        s = fmaf(rv1[j].x, cv1.x, s); s = fmaf(rv1[j].y, cv1.y, s);
        s = fmaf(rv1[j].z, cv1.z, s); s = fmaf(rv1[j].w, cv1.w, s);
        acc[j][q] = s;
      }
    }
  }
  // transform to negdist = 2*dot - xx_r - xx_m, then to sortable uints
  float xxm[16];
  #pragma unroll
  for (int q = 0; q < 16; ++q) xxm[q] = xx[b*ND + q*64 + lane];
  unsigned uk[4][16];
  #pragma unroll
  for (int j = 0; j < 4; ++j){
    float xr = xx[b*ND + r0 + w*4 + j];
    #pragma unroll
    for (int q = 0; q < 16; ++q){
      float f = 2.f*acc[j][q] - xr - xxm[q];
      unsigned bv = __float_as_uint(f);
      uk[j][q] = (bv & 0x80000000u) ? ~bv : (bv | 0x80000000u);  // order-preserving
    }
  }
  // radix binary search for T = 20th-largest key per row; counts via ballot+popcount
  unsigned pref[4] = {0u, 0u, 0u, 0u};
  #pragma unroll 1
  for (int bit = 31; bit >= 0; --bit){
    #pragma unroll
    for (int u = 0; u < 4; ++u){
      unsigned cand = pref[u] | (1u << bit);
      int c = 0;
      #pragma unroll
      for (int q = 0; q < 16; ++q)
        c += (int)__popcll(__ballot(uk[u][q] >= cand));
      if (c >= KNN) pref[u] = cand;
    }
  }
  // emit: all keys > T, plus lowest-global-index keys == T to fill to 20
  unsigned long long mlt = (1ull << lane) - 1ull;   // lanes below me
  #pragma unroll
  for (int u = 0; u < 4; ++u){
    unsigned T = pref[u];
    int cg = 0;
    #pragma unroll
    for (int q = 0; q < 16; ++q) cg += (int)__popcll(__ballot(uk[u][q] > T));
    int need_eq = KNN - cg;                          // >= 1 by construction
    int* op = &idxp[((size_t)(b*ND + r0 + w*4 + u))*KNN];
    int run_gt = 0, run_eq = 0;
    #pragma unroll
    for (int q = 0; q < 16; ++q){
      unsigned k = uk[u][q];
      unsigned long long bg = __ballot(k > T);
      unsigned long long be = __ballot(k == T);
      if (k > T) op[run_gt + (int)__popcll(bg & mlt)] = q*64 + lane;
      if (k == T){
        int r = run_eq + (int)__popcll(be & mlt);
        if (r < need_eq) op[cg + r] = q*64 + lane;
      }
      run_gt += (int)__popcll(bg);
      run_eq += (int)__popcll(be);
    }
  }
}

// ------ phase A (register-blocked): zs=alpha*W1.x ; cc=(dW.x+bias)*alpha+beta --------
template<int O>
__global__ __launch_bounds__(256) void k_phaseA(const float* __restrict__ x,
    const float* __restrict__ W, const float* __restrict__ bias,
    const float* __restrict__ gamma, const float* __restrict__ beta,
    float* __restrict__ zs, float* __restrict__ ccv, int C, int XS){
  constexpr int TO = O/16;
  constexpr int WP = O + 4;
  __shared__ float W1s[32*WP];
  __shared__ float dWs[32*WP];
  __shared__ float Xs[32*33];
  int blk = blockIdx.x;
  int b = blk >> 5, n0 = (blk & 31)*32;
  int t = threadIdx.x;
  int ot = t & 15, nt = t >> 4;
  int obase = ot*TO;
  int nl = nt*2;
  float az[TO][2] = {}, ac[TO][2] = {};
  for (int cc = 0; cc < C; cc += 32){
    int KC = (C - cc < 32) ? (C - cc) : 32;
    for (int i = t; i < O*KC; i += 256){
      int o = i % O, c = i / O;
      float w1 = W[(size_t)o*2*C + cc + c];
      float w2 = W[(size_t)o*2*C + C + cc + c];
      W1s[c*WP + o] = w1;
      dWs[c*WP + o] = w2 - w1;
    }
    for (int i = t; i < 32*KC; i += 256){
      int c = i % KC, row = i / KC;
      Xs[c*33 + row] = x[((size_t)b*ND + n0 + row)*XS + cc + c];
    }
    __syncthreads();
    for (int c = 0; c < KC; ++c){
      float xv0 = Xs[c*33 + nl];
      float xv1 = Xs[c*33 + nl + 1];
      #pragma unroll
      for (int i = 0; i < TO; ++i){
        float w1 = W1s[c*WP + obase + i];
        float dw = dWs[c*WP + obase + i];
        az[i][0] = fmaf(w1, xv0, az[i][0]);
        az[i][1] = fmaf(w1, xv1, az[i][1]);
        ac[i][0] = fmaf(dw, xv0, ac[i][0]);
        ac[i][1] = fmaf(dw, xv1, ac[i][1]);
      }
    }
    __syncthreads();
  }
  #pragma unroll
  for (int i = 0; i < TO; ++i){
    int o = obase + i;
    float alpha = gamma[o]*BNSC;
    float bb = bias[o], be = beta[o];
    #pragma unroll
    for (int q = 0; q < 2; ++q){
      int n = n0 + nl + q;
      size_t off = ((size_t)b*ND + n)*O + o;
      zs[off]  = az[i][q]*alpha;
      ccv[off] = fmaf(ac[i][q] + bb, alpha, be);
    }
  }
}

// ------ phase B: out[b,n,o] = max_k leaky(zs[b,idx_k,o]+cc[b,n,o]); optional xx ------
template<bool DOXX>
__global__ __launch_bounds__(256) void k_phaseB(const float* __restrict__ zs,
    const float* __restrict__ ccv, const int* __restrict__ idxp,
    float* __restrict__ outp, float* __restrict__ xxout,
    int O, int ostride, int ooff){
  int t = threadIdx.x;
  int lane = t & 63, w = t >> 6;
  int gn = blockIdx.x*4 + w;
  int b = gn >> 10;
  int mm[KNN];
  const int* ip = idxp + (size_t)gn*KNN;
  #pragma unroll
  for (int k = 0; k < KNN; ++k) mm[k] = ip[k];
  float sq = 0.f;
  for (int o = lane; o < O; o += 64){
    float cvv = ccv[(size_t)gn*O + o];
    float mx = -INFINITY;
    #pragma unroll 4
    for (int k = 0; k < KNN; ++k){
      float v = leakyf(zs[((size_t)(b*ND) + mm[k])*O + o] + cvv);
      mx = fmaxf(mx, v);
    }
    outp[(size_t)gn*ostride + ooff + o] = mx;
    if (DOXX) sq = fmaf(mx, mx, sq);
  }
  if (DOXX){
    #pragma unroll
    for (int off = 32; off; off >>= 1) sq += __shfl_down(sq, off);
    if (lane == 0) xxout[gn] = sq;
  }
}

// ---------------- qkv[bn,o] = fuse[bn,:].Wi[o,:] + bi[o]  (raw Wi, float4) -----------
__global__ __launch_bounds__(256) void k_lin(const float* __restrict__ in,
    const float* __restrict__ Wm, const float* __restrict__ bias,
    float* __restrict__ outp){
  int gid = blockIdx.x*256 + threadIdx.x;
  if (gid >= BD*ND*192) return;
  int o = gid % 192; int bn = gid / 192;
  const float4* ip = (const float4*)(in + (size_t)bn*64);
  const float4* wp = (const float4*)(Wm + (size_t)o*64);
  float s = bias[o];
  #pragma unroll
  for (int c = 0; c < 16; ++c){
    float4 a = ip[c], wv = wp[c];
    s = fmaf(a.x, wv.x, s); s = fmaf(a.y, wv.y, s);
    s = fmaf(a.z, wv.z, s); s = fmaf(a.w, wv.w, s);
  }
  outp[gid] = s;
}

// ------- flash-decode attention (no-max exp): 2 heads/block, 8 queries/thread --------
__global__ __launch_bounds__(256, 1) void k_attn_part(const float* __restrict__ qkv,
    float* __restrict__ pl, float* __restrict__ pacc){
  __shared__ __align__(16) float Ks[2][KPS*8];
  __shared__ __align__(16) float Vs[2][KPS*8];
  int blk = blockIdx.x;                // b(8) x hp(4) x ksl(8) = 256 blocks
  int ksl = blk & 7; int hp = (blk >> 3) & 3; int b = blk >> 5;
  int t = threadIdx.x;
  int hh = t >> 7;                     // wave-uniform head select within pair
  int h = hp*2 + hh;
  int lq = t & 127;
  for (int i = t; i < 2*KPS*8; i += 256){
    int hi = (i >= KPS*8) ? 1 : 0;
    int r = i - hi*KPS*8;
    int m = r >> 3, dd = r & 7;
    size_t base = ((size_t)b*ND + ksl*KPS + m)*192 + (hp*2 + hi)*8 + dd;
    Ks[hi][r] = qkv[base + 64];
    Vs[hi][r] = qkv[base + 128];
  }
  __syncthreads();
  const float scale = 0.35355339059327373f;
  float q[8][8];
  #pragma unroll
  for (int u = 0; u < 8; ++u){
    int n = u*128 + lq;
    const float4* qp = (const float4*)(qkv + ((size_t)b*ND + n)*192 + h*8);
    float4 q0 = qp[0], q1 = qp[1];
    q[u][0]=q0.x*scale; q[u][1]=q0.y*scale; q[u][2]=q0.z*scale; q[u][3]=q0.w*scale;
    q[u][4]=q1.x*scale; q[u][5]=q1.y*scale; q[u][6]=q1.z*scale; q[u][7]=q1.w*scale;
  }
  float l[8] = {};
  float acc[8][8] = {};
  for (int m = 0; m < KPS; ++m){
    float4 k0 = *(const float4*)&Ks[hh][m*8];
    float4 k1 = *(const float4*)&Ks[hh][m*8+4];
    float4 v0 = *(const float4*)&Vs[hh][m*8];
    float4 v1 = *(const float4*)&Vs[hh][m*8+4];
    #pragma unroll
    for (int u = 0; u < 8; ++u){
      float s;
      s = q[u][0]*k0.x;           s = fmaf(q[u][1], k0.y, s);
      s = fmaf(q[u][2], k0.z, s); s = fmaf(q[u][3], k0.w, s);
      s = fmaf(q[u][4], k1.x, s); s = fmaf(q[u][5], k1.y, s);
      s = fmaf(q[u][6], k1.z, s); s = fmaf(q[u][7], k1.w, s);
      float p = __expf(s);        // scores tiny: exp-without-max is safe; merge = sum
      l[u] += p;
      acc[u][0] = fmaf(p, v0.x, acc[u][0]);
      acc[u][1] = fmaf(p, v0.y, acc[u][1]);
      acc[u][2] = fmaf(p, v0.z, acc[u][2]);
      acc[u][3] = fmaf(p, v0.w, acc[u][3]);
      acc[u][4] = fmaf(p, v1.x, acc[u][4]);
      acc[u][5] = fmaf(p, v1.y, acc[u][5]);
      acc[u][6] = fmaf(p, v1.z, acc[u][6]);
      acc[u][7] = fmaf(p, v1.w, acc[u][7]);
    }
  }
  #pragma unroll
  for (int u = 0; u < 8; ++u){
    int n = u*128 + lq;
    size_t pidx = (((size_t)(b*8 + h))*8 + ksl)*ND + n;
    pl[pidx] = l[u];
    float4* ap = (float4*)&pacc[pidx*8];
    ap[0] = make_float4(acc[u][0], acc[u][1], acc[u][2], acc[u][3]);
    ap[1] = make_float4(acc[u][4], acc[u][5], acc[u][6], acc[u][7]);
  }
}

// ------- flash-decode combine: plain sums (no max bookkeeping) -----------------------
__global__ __launch_bounds__(256) void k_attn_comb(const float* __restrict__ pl,
    const float* __restrict__ pacc, float* __restrict__ attno){
  int gid = blockIdx.x*256 + threadIdx.x;   // (b*8+h)*1024+n, total 65536
  if (gid >= BD*8*ND) return;
  int n = gid & 1023; int bh = gid >> 10;
  int h = bh & 7; int b = bh >> 3;
  float L = 0.f;
  float o[8] = {};
  #pragma unroll
  for (int s = 0; s < KSL; ++s){
    size_t pidx = ((size_t)bh*8 + s)*ND + n;
    L += pl[pidx];
    const float4* ap = (const float4*)&pacc[pidx*8];
    float4 a0 = ap[0], a1 = ap[1];
    o[0] += a0.x; o[1] += a0.y; o[2] += a0.z; o[3] += a0.w;
    o[4] += a1.x; o[5] += a1.y; o[6] += a1.z; o[7] += a1.w;
  }
  float inv = 1.f/L;
  float4* dst = (float4*)&attno[((size_t)b*ND + n)*64 + h*8];
  dst[0] = make_float4(o[0]*inv, o[1]*inv, o[2]*inv, o[3]*inv);
  dst[1] = make_float4(o[4]*inv, o[5]*inv, o[6]*inv, o[7]*inv);
}

// ------- out-proj + pair-mean: emb[bn,f] = 0.5*(proj[2f]+proj[2f+1]) (raw Wo) --------
__global__ __launch_bounds__(256) void k_projmean(const float* __restrict__ attno,
    const float* __restrict__ Wo, const float* __restrict__ bo,
    float* __restrict__ emb){
  int gid = blockIdx.x*256 + threadIdx.x;
  if (gid >= BD*ND*32) return;
  int f = gid % 32; int bn = gid / 32;
  const float4* ip = (const float4*)(attno + (size_t)bn*64);
  int o0 = 2*f, o1 = 2*f + 1;
  const float4* w0 = (const float4*)(Wo + (size_t)o0*64);
  const float4* w1 = (const float4*)(Wo + (size_t)o1*64);
  float s0 = bo[o0], s1 = bo[o1];
  #pragma unroll
  for (int c = 0; c < 16; ++c){
    float4 a = ip[c], u = w0[c], v = w1[c];
    s0 = fmaf(a.x,u.x,s0); s0 = fmaf(a.y,u.y,s0); s0 = fmaf(a.z,u.z,s0); s0 = fmaf(a.w,u.w,s0);
    s1 = fmaf(a.x,v.x,s1); s1 = fmaf(a.y,v.y,s1); s1 = fmaf(a.z,v.z,s1); s1 = fmaf(a.w,v.w,s1);
  }
  emb[gid] = 0.5f*(s0 + s1);
}

// ---------------- fused attention pool: g, scores, pooled (one block per b) ----------
__global__ __launch_bounds__(256) void k_poolfuse(const float* __restrict__ emb,
    const float* __restrict__ attw, float* __restrict__ sout,
    float* __restrict__ pooled){
  __shared__ float part[8][32];
  __shared__ float meanv[32];
  __shared__ float gv[32];
  __shared__ float sc[ND];
  int b = blockIdx.x, t = threadIdx.x;
  int f = t & 31, j = t >> 5;
  const float* eb = emb + (size_t)b*ND*32;
  float s = 0.f;
  for (int n = j; n < ND; n += 8) s += eb[n*32 + f];
  part[j][f] = s;
  __syncthreads();
  if (t < 32){
    float m = 0.f;
    for (int j2 = 0; j2 < 8; ++j2) m += part[j2][t];
    meanv[t] = m * (1.f/ND);
  }
  __syncthreads();
  if (t < 32){
    float acc = 0.f;
    for (int f2 = 0; f2 < 32; ++f2) acc = fmaf(meanv[f2], attw[f2*32 + t], acc);
    gv[t] = tanhf(acc);
  }
  __syncthreads();
  for (int n = t; n < ND; n += 256){
    const float4* ep = (const float4*)(eb + n*32);
    float acc = 0.f;
    #pragma unroll
    for (int f4 = 0; f4 < 8; ++f4){
      float4 e = ep[f4];
      acc = fmaf(e.x, gv[f4*4+0], acc);
      acc = fmaf(e.y, gv[f4*4+1], acc);
      acc = fmaf(e.z, gv[f4*4+2], acc);
      acc = fmaf(e.w, gv[f4*4+3], acc);
    }
    float sg = 1.f/(1.f + __expf(-acc));
    sout[b*ND + n] = sg;
    sc[n] = sg;
  }
  __syncthreads();
  float pacc = 0.f;
  for (int n = j; n < ND; n += 8) pacc = fmaf(eb[n*32 + f], sc[n], pacc);
  part[j][f] = pacc;
  __syncthreads();
  if (t < 32){
    float m = 0.f;
    for (int j2 = 0; j2 < 8; ++j2) m += part[j2][t];
    pooled[b*32 + t] = m;
  }
}

// ---------------- NTN head: LDS-staged weights (2-phase, 32KB each) ----------------
__global__ __launch_bounds__(256) void k_head(const float* __restrict__ p1,
    const float* __restrict__ p2, const float* __restrict__ ntnw,
    const float* __restrict__ ntnv, const float* __restrict__ ntnb,
    const float* __restrict__ fc1w, const float* __restrict__ fc1b,
    const float* __restrict__ scw, const float* __restrict__ scb,
    float* __restrict__ outscore){
  __shared__ __align__(16) float Wl[8192];
  __shared__ float Vl[512];
  __shared__ float F1[256];
  __shared__ float ds[8][32];
  __shared__ float tv[8][16];
  __shared__ float hv[8][16];
  int t = threadIdx.x;
  {
    int b = t >> 5, f = t & 31;
    ds[b][f] = p1[b*32+f] - p2[b*32+f];
  }
  for (int i = t; i < 512; i += 256) Vl[i] = ntnv[i];
  if (t < 256) F1[t] = fc1w[t];
  float acc = 0.f;
  for (int ph = 0; ph < 2; ++ph){
    __syncthreads();
    {
      const float4* src = (const float4*)(ntnw + ph*8192);
      float4* dst = (float4*)Wl;
      for (int i = t; i < 2048; i += 256) dst[i] = src[i];
    }
    __syncthreads();
    if (t < 128){
      int b = t >> 4, tt = t & 15;
      for (int fi = 0; fi < 16; ++fi){
        float df = ds[b][ph*16 + fi];
        #pragma unroll 8
        for (int gg = 0; gg < 32; ++gg)
          acc = fmaf(df*ds[b][gg], Wl[(fi*32+gg)*16 + tt], acc);
      }
    }
  }
  if (t < 128){
    int b = t >> 4, tt = t & 15;
    acc += ntnb[tt];
    for (int gg = 0; gg < 32; ++gg) acc = fmaf(ds[b][gg], Vl[tt*32+gg], acc);
    tv[b][tt] = fmaxf(acc, 0.f);
  }
  __syncthreads();
  if (t < 128){
    int b = t >> 4, i = t & 15;
    float a2 = fc1b[i];
    for (int kk = 0; kk < 16; ++kk) a2 = fmaf(tv[b][kk], F1[i*16+kk], a2);
    hv[b][i] = fmaxf(a2, 0.f);
  }
  __syncthreads();
  if (t < 8){
    float a3 = scb[0];
    for (int i = 0; i < 16; ++i) a3 = fmaf(hv[t][i], scw[i], a3);
    outscore[t] = 1.f/(1.f + __expf(-a3));
  }
}

// =====================================================================================
extern "C" void kernel_launch(void* const* d_in, const int* in_sizes, int n_in,
                              void* d_out, int out_size, void* d_ws, size_t ws_size,
                              hipStream_t stream) {
  auto F = [&](int i){ return (const float*)d_in[i]; };
  const float* feats[2] = { F(0), F(1) };
  const float* cw[3] = { F(2), F(6), F(10) };
  const float* cb[3] = { F(3), F(7), F(11) };
  const float* cg[3] = { F(4), F(8), F(12) };
  const float* cB[3] = { F(5), F(9), F(13) };
  const float* sw[3] = { F(14), F(18), F(22) };
  const float* sb[3] = { F(15), F(19), F(23) };
  const float* sg[3] = { F(16), F(20), F(24) };
  const float* sB[3] = { F(17), F(21), F(25) };
  const float* mha_wi = F(26); const float* mha_bi = F(27);
  const float* mha_wo = F(28); const float* mha_bo = F(29);
  const float* att_w  = F(30);
  const float* ntn_w  = F(31); const float* ntn_v = F(32); const float* ntn_b = F(33);
  const float* fc1_w  = F(34); const float* fc1_b = F(35);
  const float* sc_w   = F(36); const float* sc_b  = F(37);
  float* out = (float*)d_out;

  char* ws = (char*)d_ws;
  // MHA scratch in the low region (formerly negdist; knn no longer writes it)
  float* qkv   = (float*)ws;                              // [0, 6 MiB)
  float* attno = (float*)(ws + ((size_t)8  << 20));       // [8, 10 MiB)
  float* plb   = (float*)(ws + ((size_t)10 << 20));       // [10, 12 MiB)
  float* paccb = (float*)(ws + ((size_t)14 << 20));       // [14, 30 MiB)
  size_t off = 33554432;
  float* xA   = (float*)(ws + off); off += 4194304;
  float* xB   = (float*)(ws + off); off += 4194304;
  float* zs   = (float*)(ws + off); off += 4194304;
  float* cvb  = (float*)(ws + off); off += 4194304;
  int*   idxb = (int*)  (ws + off); off += 655360;
  float* xxb  = (float*)(ws + off); off += 32768;
  float* fuse = (float*)(ws + off); off += 2097152;
  float* emb1 = (float*)(ws + off); off += 1048576;
  float* emb2 = (float*)(ws + off); off += 1048576;
  float* pool1= (float*)(ws + off); off += 4096;
  float* pool2= (float*)(ws + off); off += 4096;

  auto knn = [&](const float* xin, int CS, int nch){
    k_knn<<<dim3(64, 8), 256, 0, stream>>>(xin, xxb, idxb, CS, nch);
  };
  auto phA = [&](const float* xin, int C, int XS, int O, const float* W, const float* bb,
                 const float* gg, const float* be){
    if (O == 64)       k_phaseA<64> <<<BD*ND/32, 256, 0, stream>>>(xin, W, bb, gg, be, zs, cvb, C, XS);
    else if (O == 128) k_phaseA<128><<<BD*ND/32, 256, 0, stream>>>(xin, W, bb, gg, be, zs, cvb, C, XS);
    else               k_phaseA<32> <<<BD*ND/32, 256, 0, stream>>>(xin, W, bb, gg, be, zs, cvb, C, XS);
  };

  for (int br = 0; br < 2; ++br){
    const float* feat = feats[br];
    float* emb    = br ? emb2  : emb1;
    float* sout   = out + 8 + br*(BD*ND);
    float* pooled = br ? pool2 : pool1;
    for (int part = 0; part < 2; ++part){
      const float* const* Wl = part ? sw : cw;
      const float* const* bl = part ? sb : cb;
      const float* const* gl = part ? sg : cg;
      const float* const* Bl = part ? sB : cB;
      int C0 = part ? 12 : 3;
      int CS0 = part ? 12 : 4;
      // layer 0: C0 -> 64
      if (part) k_prep<12,12><<<BD*ND/256, 256, 0, stream>>>(feat, xA, xxb, 3);
      else      k_prep<3, 4> <<<BD*ND/256, 256, 0, stream>>>(feat, xA, xxb, 0);
      knn(xA, CS0, part ? 2 : 1);
      phA(xA, C0, CS0, 64, Wl[0], bl[0], gl[0], Bl[0]);
      k_phaseB<true><<<BD*ND/4, 256, 0, stream>>>(zs, cvb, idxb, xB, xxb, 64, 64, 0);
      // layer 1: 64 -> 128 (xx produced by phaseB)
      knn(xB, 64, 8);
      phA(xB, 64, 64, 128, Wl[1], bl[1], gl[1], Bl[1]);
      k_phaseB<true><<<BD*ND/4, 256, 0, stream>>>(zs, cvb, idxb, xA, xxb, 128, 128, 0);
      // layer 2: 128 -> 32, written into fuse at column offset
      knn(xA, 128, 16);
      phA(xA, 128, 128, 32, Wl[2], bl[2], gl[2], Bl[2]);
      k_phaseB<false><<<BD*ND/4, 256, 0, stream>>>(zs, cvb, idxb, fuse, nullptr, 32, 64, part*32);
    }
    // MHA (flash-decode, no-max exp)
    k_lin<<<(BD*ND*192)/256, 256, 0, stream>>>(fuse, mha_wi, mha_bi, qkv);
    k_attn_part<<<BD*4*KSL, 256, 0, stream>>>(qkv, plb, paccb);
    k_attn_comb<<<(BD*8*ND)/256, 256, 0, stream>>>(plb, paccb, attno);
    k_projmean<<<(BD*ND*32)/256, 256, 0, stream>>>(attno, mha_wo, mha_bo, emb);
    // fused attention pool
    k_poolfuse<<<BD, 256, 0, stream>>>(emb, att_w, sout, pooled);
  }
  k_head<<<1, 256, 0, stream>>>(pool1, pool2, ntn_w, ntn_v, ntn_b,
                                fc1_w, fc1_b, sc_w, sc_b, out);
}